// Round 1
// baseline (48402.600 us; speedup 1.0000x reference)
//
#include <hip/hip_runtime.h>
#include <hip/hip_bf16.h>
#include <stdint.h>

// Problem constants
#define B_   128
#define S_   1024
#define EMB_ 256
#define HID_ 512

typedef __attribute__((ext_vector_type(8))) short bf16x8;
typedef __attribute__((ext_vector_type(4))) float f32x4;
typedef __attribute__((ext_vector_type(4))) uint32_t u32x4;

// d_ws layout (bytes). Total need: ~272.5 MB.
#define OFF_HH    0u                  // hh_all [1024 s][32 kc][128 b][32 k] bf16 = 256MB
#define OFF_WIX   268435456u          // w_i_x bf16 [512][256]
#define OFF_WIP   268697600u          // w_i_p bf16 [32 rank][16 kc][16 r][32 k]
#define OFF_WH    269221888u          // w_h   bf16 same blocking
#define OFF_WPV   269746176u          // pv_w  bf16 [32 rank][32 kc][16 r][32 k]
#define OFF_SW1   270794752u          // sem_w1 bf16 [512][1024]
#define OFF_SW2   271843328u          // sem_w2 bf16 [256][512]
#define OFF_RN    272105472u          // rn f32 [128][256]
#define OFF_OPP   272236544u          // 8 groups x [32 cu][16 b][6] f32
#define OFF_PEEKS 272334848u          // 8 groups x [16 kc][16 b][32 k] bf16
#define OFF_BAR   272465920u          // 8 groups x 32 u32 (128B apart)

__device__ __forceinline__ f32x4 mfma16(bf16x8 a, bf16x8 b, f32x4 c) {
  return __builtin_amdgcn_mfma_f32_16x16x32_bf16(a, b, c, 0, 0, 0);
}
__device__ __forceinline__ uint16_t f2bf(float x) {
  union { float f; uint32_t u; } v; v.f = x;
  return (uint16_t)((v.u + 0x7FFFu + ((v.u >> 16) & 1u)) >> 16);  // RNE
}
__device__ __forceinline__ float bf2f(uint16_t h) {
  union { uint32_t u; float f; } v; v.u = ((uint32_t)h) << 16;
  return v.f;
}

// ---------------------------------------------------------------------------
// K_conv: convert & re-layout all weights to bf16 in ws; zero barrier counters
// ---------------------------------------------------------------------------
__global__ void k_conv(const float* __restrict__ wi, const float* __restrict__ wh,
                       const float* __restrict__ pvw, const float* __restrict__ sw1,
                       const float* __restrict__ sw2, uint8_t* __restrict__ ws) {
  uint16_t* wix = (uint16_t*)(ws + OFF_WIX);
  uint16_t* wip = (uint16_t*)(ws + OFF_WIP);
  uint16_t* whc = (uint16_t*)(ws + OFF_WH);
  uint16_t* wpv = (uint16_t*)(ws + OFF_WPV);
  uint16_t* s1b = (uint16_t*)(ws + OFF_SW1);
  uint16_t* s2b = (uint16_t*)(ws + OFF_SW2);
  int tid = blockIdx.x * blockDim.x + threadIdx.x;
  int nth = gridDim.x * blockDim.x;
  for (int i = tid; i < 512*256; i += nth) {
    int r = i >> 8, e = i & 255;
    wix[i] = f2bf(wi[r*768 + e]);
  }
  for (int i = tid; i < 512*512; i += nth) {
    int rank = i >> 13, rem = i & 8191;
    int kc = rem >> 9, ii = (rem >> 5) & 15, kk = rem & 31;
    wip[i] = f2bf(wi[(rank*16 + ii)*768 + 256 + kc*32 + kk]);
  }
  for (int i = tid; i < 512*512; i += nth) {
    int rank = i >> 13, rem = i & 8191;
    int kc = rem >> 9, ii = (rem >> 5) & 15, kk = rem & 31;
    whc[i] = f2bf(wh[(rank*16 + ii)*512 + kc*32 + kk]);
  }
  for (int i = tid; i < 512*1024; i += nth) {
    int rank = i >> 14, rem = i & 16383;
    int kc = rem >> 9, ii = (rem >> 5) & 15, kk = rem & 31;
    wpv[i] = f2bf(pvw[(rank*16 + ii)*1024 + kc*32 + kk]);
  }
  for (int i = tid; i < 512*1024; i += nth) s1b[i] = f2bf(sw1[i]);
  for (int i = tid; i < 256*512; i += nth) s2b[i] = f2bf(sw2[i]);
  if (tid < 256) ((uint32_t*)(ws + OFF_BAR))[tid] = 0u;
}

// ---------------------------------------------------------------------------
// K_rn: rn[b][e] = 1 / max(||emb[ids[b,:]][e]||_2 over s, 1e-12)
// ---------------------------------------------------------------------------
__global__ __launch_bounds__(256, 1) void k_rn(const int* __restrict__ ids,
                                               const float* __restrict__ emb,
                                               uint8_t* __restrict__ ws) {
  float* rn = (float*)(ws + OFF_RN);
  int b = blockIdx.x;
  int e = threadIdx.x;
  const int* idr = ids + (size_t)b * S_;
  float acc = 0.f;
  for (int s = 0; s < S_; ++s) {
    int id = idr[s];
    float v = emb[(size_t)id * EMB_ + e];
    acc += v * v;
  }
  rn[b * EMB_ + e] = 1.f / fmaxf(sqrtf(acc), 1e-12f);
}

// ---------------------------------------------------------------------------
// K_rix: ri_x[s][r][b] (bf16, stored in d_out) = (emb[ids[b,s]]*rn[b]) @ w_i_x^T
// Gather+normalize fused into the A-operand. grid 8192 = s*8 + btile
// ---------------------------------------------------------------------------
__global__ __launch_bounds__(256, 1) void k_rix(const int* __restrict__ ids,
                                                const float* __restrict__ emb,
                                                const uint8_t* __restrict__ ws,
                                                uint16_t* __restrict__ rix) {
  const uint16_t* wix = (const uint16_t*)(ws + OFF_WIX);
  const float* rn = (const float*)(ws + OFF_RN);
  int blk = blockIdx.x;
  int s = blk >> 3;
  int b16 = (blk & 7) * 16;
  int lane = threadIdx.x & 63;
  int wv = threadIdx.x >> 6;
  int bl = lane & 15, kg = lane >> 4;
  int b = b16 + bl;
  int id = ids[(size_t)b * S_ + s];
  const float* erow = emb + (size_t)id * EMB_;
  const float* rrow = rn + (size_t)b * EMB_;
  bf16x8 af[8];
#pragma unroll
  for (int kc = 0; kc < 8; ++kc) {
    int k0 = kc * 32 + kg * 8;
#pragma unroll
    for (int j = 0; j < 8; ++j)
      af[kc][j] = (short)f2bf(erow[k0 + j] * rrow[k0 + j]);
  }
  f32x4 zero = {0.f, 0.f, 0.f, 0.f};
#pragma unroll
  for (int t = 0; t < 8; ++t) {
    int rt = wv * 8 + t;
    f32x4 acc = zero;
#pragma unroll
    for (int kc = 0; kc < 8; ++kc) {
      bf16x8 wf = *(const bf16x8*)(wix + (size_t)(rt * 16 + bl) * 256 + kc * 32 + kg * 8);
      acc = mfma16(wf, af[kc], acc);  // D[r][b]
    }
#pragma unroll
    for (int q = 0; q < 4; ++q) {
      int r = rt * 16 + kg * 4 + q;
      rix[(size_t)(s * 512 + r) * 128 + b16 + bl] = f2bf(acc[q]);
    }
  }
}

// ---------------------------------------------------------------------------
// group barrier: 32 WGs of one group, monotonic counter, device-scope
// ---------------------------------------------------------------------------
__device__ __forceinline__ void group_barrier(uint32_t* bar, uint32_t target) {
  __threadfence();  // release: drain stores, push to coherence point
  if (threadIdx.x == 0) {
    __hip_atomic_fetch_add(bar, 1u, __ATOMIC_ACQ_REL, __HIP_MEMORY_SCOPE_AGENT);
    while (__hip_atomic_load(bar, __ATOMIC_ACQUIRE, __HIP_MEMORY_SCOPE_AGENT) < target) {
      __builtin_amdgcn_s_sleep(1);
    }
  }
  __syncthreads();
  __threadfence();  // acquire: invalidate L1 so we see peers' fresh data
}

// ---------------------------------------------------------------------------
// K_scan: the sequential pass. 256 WGs x 64 thr. 8 groups (XCD) x 32 CUs.
// Group handles 16 batch elems; CU owns 16 rows of HID (phase A) and 16 rows
// of K*E=512 (phase B). Weights LDS-resident (64KB dynamic).
// ---------------------------------------------------------------------------
__global__ __launch_bounds__(64, 1) void k_scan(const float* __restrict__ opsw,
                                                const float* __restrict__ pvb,
                                                uint8_t* __restrict__ ws,
                                                const uint16_t* __restrict__ rix) {
  extern __shared__ uint8_t lds[];
  const int lane = threadIdx.x;
  const int bl = lane & 15;
  const int kg = lane >> 4;
  const int g = blockIdx.x & 7;
  const int rank = blockIdx.x >> 3;
  const int b0 = g * 16;

  {  // stage weight slices into LDS (layouts match: straight copy)
    const u32x4* swip = (const u32x4*)(ws + OFF_WIP) + (size_t)rank * 1024;
    const u32x4* swh  = (const u32x4*)(ws + OFF_WH)  + (size_t)rank * 1024;
    const u32x4* swpv = (const u32x4*)(ws + OFF_WPV) + (size_t)rank * 2048;
    u32x4* dwip = (u32x4*)lds;
    u32x4* dwh  = (u32x4*)(lds + 16384);
    u32x4* dwpv = (u32x4*)(lds + 32768);
    for (int i = lane; i < 1024; i += 64) dwip[i] = swip[i];
    for (int i = lane; i < 1024; i += 64) dwh[i] = swh[i];
    for (int i = lane; i < 2048; i += 64) dwpv[i] = swpv[i];
  }
  __syncthreads();

  float c1[4][6], c2[4][6], pb[4];
#pragma unroll
  for (int q = 0; q < 4; ++q) {
    int r = rank * 16 + kg * 4 + q;
#pragma unroll
    for (int t6 = 0; t6 < 6; ++t6) {
      c1[q][t6] = opsw[t6 * 1024 + r];
      c2[q][t6] = opsw[t6 * 1024 + 512 + r];
    }
    pb[q] = pvb[r];
  }
  const int ksown = rank >> 4;  // which stack this CU's pv rows belong to
  float stk[4][12];
#pragma unroll
  for (int q = 0; q < 4; ++q)
#pragma unroll
    for (int d = 0; d < 12; ++d) stk[q][d] = 0.f;

  uint8_t* hhbase = ws + OFF_HH;
  uint8_t* peeks = ws + OFF_PEEKS + (size_t)g * 16384;
  float* opp = (float*)(ws + OFF_OPP + (size_t)g * 12288);
  uint32_t* bar = (uint32_t*)(ws + OFF_BAR) + g * 32;

  const int kcA = rank >> 1;
  const int kA = (rank & 1) * 16;
  const uint8_t* ldwip = lds;
  const uint8_t* ldwh = lds + 16384;
  const uint8_t* ldwpv = lds + 32768;
  f32x4 zero = {0.f, 0.f, 0.f, 0.f};

  for (int s = 0; s < S_; ++s) {
    uint8_t* hhs = hhbase + (size_t)s * 262144;
    // ---------------- Phase A: ri_p + rh -> h1,h2 -> hh; ops partials -------
    f32x4 ri = zero, rh = zero;
    if (s > 0) {
      const uint8_t* hhp = hhbase + (size_t)(s - 1) * 262144;
#pragma unroll
      for (int kc = 0; kc < 16; ++kc) {
        bf16x8 pk = *(const bf16x8*)(peeks + kc * 1024 + bl * 64 + kg * 16);
        bf16x8 w1 = *(const bf16x8*)(ldwip + kc * 1024 + bl * 64 + kg * 16);
        ri = mfma16(w1, pk, ri);  // D[r][b]
        bf16x8 hf = *(const bf16x8*)(hhp + kc * 8192 + (b0 + bl) * 64 + kg * 16);
        bf16x8 w2 = *(const bf16x8*)(ldwh + kc * 1024 + bl * 64 + kg * 16);
        rh = mfma16(w2, hf, rh);
      }
    }
    float opq[6] = {0, 0, 0, 0, 0, 0};
#pragma unroll
    for (int q = 0; q < 4; ++q) {
      int r = rank * 16 + kg * 4 + q;
      float rx = bf2f(rix[(size_t)(s * 512 + r) * 128 + b0 + bl]);
      float a = ri[q] + rx + rh[q];
      float b2 = ri[q] + rx - rh[q];
      float h1 = a > 0.f ? a : 0.f;
      float h2 = b2 > 0.f ? b2 : 0.f;
#pragma unroll
      for (int t6 = 0; t6 < 6; ++t6) opq[t6] += h1 * c1[q][t6] + h2 * c2[q][t6];
      int kk = kA + kg * 4 + q;
      *(uint16_t*)(hhs + (size_t)kcA * 8192 + (b0 + bl) * 64 + kk * 2) = f2bf(h1);
      *(uint16_t*)(hhs + (size_t)(16 + kcA) * 8192 + (b0 + bl) * 64 + kk * 2) = f2bf(h2);
    }
#pragma unroll
    for (int t6 = 0; t6 < 6; ++t6) {
      float v = opq[t6];
      v += __shfl_xor(v, 16, 64);
      v += __shfl_xor(v, 32, 64);
      opq[t6] = v;
    }
    if (kg == 0) {
#pragma unroll
      for (int t6 = 0; t6 < 6; ++t6) opp[rank * 96 + bl * 6 + t6] = opq[t6];
    }
    group_barrier(bar, 32u * (uint32_t)(2 * s + 1));

    // ---------------- Phase B: ops softmax, pv, stack update, peeks --------
    float lg0 = 0.f, lg1 = 0.f, lg2 = 0.f;
#pragma unroll
    for (int i = 0; i < 8; ++i) {
      int cu = kg + i * 4;
      const float* p = opp + cu * 96 + bl * 6 + ksown * 3;
      lg0 += p[0]; lg1 += p[1]; lg2 += p[2];
    }
    lg0 += __shfl_xor(lg0, 16, 64); lg0 += __shfl_xor(lg0, 32, 64);
    lg1 += __shfl_xor(lg1, 16, 64); lg1 += __shfl_xor(lg1, 32, 64);
    lg2 += __shfl_xor(lg2, 16, 64); lg2 += __shfl_xor(lg2, 32, 64);
    float mx = fmaxf(lg0, fmaxf(lg1, lg2));
    float e0 = __expf(lg0 - mx), e1 = __expf(lg1 - mx), e2 = __expf(lg2 - mx);
    float rden = 1.f / (e0 + e1 + e2);
    float push = e0 * rden, pop = e1 * rden, nop = e2 * rden;

    f32x4 pv0 = zero, pv1 = zero;
#pragma unroll
    for (int kc = 0; kc < 32; kc += 2) {
      bf16x8 a0 = *(const bf16x8*)(hhs + (size_t)kc * 8192 + (b0 + bl) * 64 + kg * 16);
      bf16x8 w0 = *(const bf16x8*)(ldwpv + kc * 1024 + bl * 64 + kg * 16);
      pv0 = mfma16(w0, a0, pv0);
      bf16x8 a1 = *(const bf16x8*)(hhs + (size_t)(kc + 1) * 8192 + (b0 + bl) * 64 + kg * 16);
      bf16x8 w1 = *(const bf16x8*)(ldwpv + (kc + 1) * 1024 + bl * 64 + kg * 16);
      pv1 = mfma16(w1, a1, pv1);
    }
#pragma unroll
    for (int q = 0; q < 4; ++q) {
      float pvv = pv0[q] + pv1[q] + pb[q];
      float prev = stk[q][0];
      stk[q][0] = push * pvv + pop * stk[q][1] + nop * stk[q][0];
#pragma unroll
      for (int d = 1; d < 11; ++d) {
        float cur = stk[q][d];
        stk[q][d] = push * prev + pop * stk[q][d + 1] + nop * cur;
        prev = cur;
      }
      float last = stk[q][11];
      stk[q][11] = push * prev + nop * last;
      int kk = kA + kg * 4 + q;
      *(uint16_t*)(peeks + kcA * 1024 + bl * 64 + kk * 2) = f2bf(stk[q][0]);
    }
    group_barrier(bar, 32u * (uint32_t)(2 * s + 2));
  }
}

// ---------------------------------------------------------------------------
// K_sem: deferred sem head. out = normalize(relu(hh@W1^T)@W2^T) over E.
// grid 4096 = (s, b-block of 32). 4 waves: (msub, e/n-half).
// ---------------------------------------------------------------------------
__global__ __launch_bounds__(256, 1) void k_sem(const uint8_t* __restrict__ ws,
                                                float* __restrict__ out) {
  __shared__ uint16_t t1[2][16][16][32];  // [msub][n>>5][m][n&31]
  __shared__ float nrm[2][16][2];
  int mt = blockIdx.x;
  int s = mt >> 2;
  int b0 = (mt & 3) * 32;
  int lane = threadIdx.x & 63, wv = threadIdx.x >> 6;
  int msub = wv >> 1, half = wv & 1;
  int bl = lane & 15, kg = lane >> 4;
  const uint8_t* hh = ws + OFF_HH + (size_t)s * 262144;
  const uint16_t* sw1 = (const uint16_t*)(ws + OFF_SW1);
  const uint16_t* sw2 = (const uint16_t*)(ws + OFF_SW2);
  f32x4 zero = {0.f, 0.f, 0.f, 0.f};

  f32x4 acc1[16];
#pragma unroll
  for (int nt = 0; nt < 16; ++nt) acc1[nt] = zero;
  for (int kc = 0; kc < 32; ++kc) {
    bf16x8 af = *(const bf16x8*)(hh + (size_t)kc * 8192 + (b0 + msub * 16 + bl) * 64 + kg * 16);
#pragma unroll
    for (int nt = 0; nt < 16; ++nt) {
      bf16x8 wf = *(const bf16x8*)(sw1 + (size_t)(half * 256 + nt * 16 + bl) * 1024 + kc * 32 + kg * 8);
      acc1[nt] = mfma16(wf, af, acc1[nt]);  // D[n][m]
    }
  }
#pragma unroll
  for (int nt = 0; nt < 16; ++nt) {
#pragma unroll
    for (int q = 0; q < 4; ++q) {
      int n = half * 256 + nt * 16 + kg * 4 + q;
      float v = acc1[nt][q];
      v = v > 0.f ? v : 0.f;
      t1[msub][n >> 5][bl][n & 31] = f2bf(v);
    }
  }
  __syncthreads();

  f32x4 acc2[8];
#pragma unroll
  for (int et = 0; et < 8; ++et) acc2[et] = zero;
#pragma unroll
  for (int kc = 0; kc < 16; ++kc) {
    bf16x8 tf = *(const bf16x8*)(&t1[msub][kc][bl][kg * 8]);
#pragma unroll
    for (int et = 0; et < 8; ++et) {
      bf16x8 wf = *(const bf16x8*)(sw2 + (size_t)(half * 128 + et * 16 + bl) * 512 + kc * 32 + kg * 8);
      acc2[et] = mfma16(tf, wf, acc2[et]);  // D[m][e]
    }
  }
  float ss[4] = {0, 0, 0, 0};
#pragma unroll
  for (int et = 0; et < 8; ++et)
#pragma unroll
    for (int q = 0; q < 4; ++q) ss[q] += acc2[et][q] * acc2[et][q];
#pragma unroll
  for (int q = 0; q < 4; ++q) {
    float v = ss[q];
    v += __shfl_xor(v, 1, 16);
    v += __shfl_xor(v, 2, 16);
    v += __shfl_xor(v, 4, 16);
    v += __shfl_xor(v, 8, 16);
    ss[q] = v;
  }
  if (bl == 0) {
#pragma unroll
    for (int q = 0; q < 4; ++q) nrm[msub][kg * 4 + q][half] = ss[q];
  }
  __syncthreads();
  float sc[4];
#pragma unroll
  for (int q = 0; q < 4; ++q) {
    float tot = nrm[msub][kg * 4 + q][0] + nrm[msub][kg * 4 + q][1];
    sc[q] = 1.f / fmaxf(sqrtf(tot), 1e-12f);
  }
#pragma unroll
  for (int et = 0; et < 8; ++et) {
    int e = half * 128 + et * 16 + bl;
#pragma unroll
    for (int q = 0; q < 4; ++q) {
      int b = b0 + msub * 16 + kg * 4 + q;
      out[((size_t)b * S_ + s) * EMB_ + e] = acc2[et][q] * sc[q];
    }
  }
}

// ---------------------------------------------------------------------------
extern "C" void kernel_launch(void* const* d_in, const int* in_sizes, int n_in,
                              void* d_out, int out_size, void* d_ws, size_t ws_size,
                              hipStream_t stream) {
  (void)in_sizes; (void)n_in; (void)out_size; (void)ws_size;
  const int* ids = (const int*)d_in[0];
  const float* emb = (const float*)d_in[1];
  const float* wi = (const float*)d_in[2];
  const float* wh = (const float*)d_in[3];
  const float* sw1 = (const float*)d_in[4];
  const float* sw2 = (const float*)d_in[5];
  const float* pvw = (const float*)d_in[6];
  const float* pvb = (const float*)d_in[7];
  const float* opsw = (const float*)d_in[8];
  uint8_t* ws = (uint8_t*)d_ws;
  float* out = (float*)d_out;
  uint16_t* rix = (uint16_t*)d_out;  // ri_x (128MB bf16) lives in d_out until k_sem

  hipLaunchKernelGGL(k_conv, dim3(256), dim3(256), 0, stream, wi, wh, pvw, sw1, sw2, ws);
  hipLaunchKernelGGL(k_rn, dim3(128), dim3(256), 0, stream, ids, emb, ws);
  hipLaunchKernelGGL(k_rix, dim3(8192), dim3(256), 0, stream, ids, emb, ws, rix);
  hipLaunchKernelGGL(k_scan, dim3(256), dim3(64), 65536, stream, opsw, pvb, ws, rix);
  hipLaunchKernelGGL(k_sem, dim3(4096), dim3(256), 0, stream, ws, out);
}

// Round 2
// 21404.060 us; speedup vs baseline: 2.2614x; 2.2614x over previous
//
#include <hip/hip_runtime.h>
#include <hip/hip_bf16.h>
#include <stdint.h>

// Problem constants
#define B_   128
#define S_   1024
#define EMB_ 256
#define HID_ 512

typedef __attribute__((ext_vector_type(8))) short bf16x8;
typedef __attribute__((ext_vector_type(4))) float f32x4;
typedef __attribute__((ext_vector_type(4))) uint32_t u32x4;

// d_ws layout (bytes). Total need: ~272.5 MB.
#define OFF_HH    0u                  // hh_all [1024 s][32 kc][128 b][32 k] bf16 = 256MB
#define OFF_WIX   268435456u          // w_i_x bf16 [512][256]
#define OFF_WIP   268697600u          // w_i_p bf16 [32 rank][16 kc][16 r][32 k]
#define OFF_WH    269221888u          // w_h   bf16 same blocking
#define OFF_WPV   269746176u          // pv_w  bf16 [32 rank][32 kc][16 r][32 k]
#define OFF_SW1   270794752u          // sem_w1 bf16 [512][1024]
#define OFF_SW2   271843328u          // sem_w2 bf16 [256][512]
#define OFF_RN    272105472u          // rn f32 [128][256]
#define OFF_OPP   272236544u          // 8 groups x [32 cu][6 t][16 b] f32
#define OFF_PEEKS 272334848u          // 8 groups x [16 kc][16 b][32 k] bf16
#define OFF_BAR   272465920u          // 8 groups x 32 u32 (128B apart)

__device__ __forceinline__ f32x4 mfma16(bf16x8 a, bf16x8 b, f32x4 c) {
  return __builtin_amdgcn_mfma_f32_16x16x32_bf16(a, b, c, 0, 0, 0);
}
__device__ __forceinline__ uint16_t f2bf(float x) {
  union { float f; uint32_t u; } v; v.f = x;
  return (uint16_t)((v.u + 0x7FFFu + ((v.u >> 16) & 1u)) >> 16);  // RNE
}
__device__ __forceinline__ float bf2f(uint16_t h) {
  union { uint32_t u; float f; } v; v.u = ((uint32_t)h) << 16;
  return v.f;
}

// --- coherent (MALL-direct) payload access: relaxed agent-scope atomics ----
// These compile to cache-bypassing global ops (sc0 sc1), so cross-XCD
// visibility needs NO fences / L2 flushes anywhere.
__device__ __forceinline__ void st_u64(void* p, uint64_t v) {
  __hip_atomic_store((uint64_t*)p, v, __ATOMIC_RELAXED, __HIP_MEMORY_SCOPE_AGENT);
}
__device__ __forceinline__ uint64_t ld_u64(const void* p) {
  return __hip_atomic_load((const uint64_t*)p, __ATOMIC_RELAXED, __HIP_MEMORY_SCOPE_AGENT);
}
__device__ __forceinline__ void st_f32a(float* p, float v) {
  __hip_atomic_store(p, v, __ATOMIC_RELAXED, __HIP_MEMORY_SCOPE_AGENT);
}
__device__ __forceinline__ float ld_f32a(const float* p) {
  return __hip_atomic_load(p, __ATOMIC_RELAXED, __HIP_MEMORY_SCOPE_AGENT);
}
__device__ __forceinline__ bf16x8 ld_frag(const void* p) {
  union { uint64_t u[2]; bf16x8 v; } c;
  c.u[0] = ld_u64(p);
  c.u[1] = ld_u64((const uint8_t*)p + 8);
  return c.v;
}

// ---------------------------------------------------------------------------
// K_conv: convert & re-layout all weights to bf16 in ws; zero barrier counters
// ---------------------------------------------------------------------------
__global__ void k_conv(const float* __restrict__ wi, const float* __restrict__ wh,
                       const float* __restrict__ pvw, const float* __restrict__ sw1,
                       const float* __restrict__ sw2, uint8_t* __restrict__ ws) {
  uint16_t* wix = (uint16_t*)(ws + OFF_WIX);
  uint16_t* wip = (uint16_t*)(ws + OFF_WIP);
  uint16_t* whc = (uint16_t*)(ws + OFF_WH);
  uint16_t* wpv = (uint16_t*)(ws + OFF_WPV);
  uint16_t* s1b = (uint16_t*)(ws + OFF_SW1);
  uint16_t* s2b = (uint16_t*)(ws + OFF_SW2);
  int tid = blockIdx.x * blockDim.x + threadIdx.x;
  int nth = gridDim.x * blockDim.x;
  for (int i = tid; i < 512*256; i += nth) {
    int r = i >> 8, e = i & 255;
    wix[i] = f2bf(wi[r*768 + e]);
  }
  for (int i = tid; i < 512*512; i += nth) {
    int rank = i >> 13, rem = i & 8191;
    int kc = rem >> 9, ii = (rem >> 5) & 15, kk = rem & 31;
    wip[i] = f2bf(wi[(rank*16 + ii)*768 + 256 + kc*32 + kk]);
  }
  for (int i = tid; i < 512*512; i += nth) {
    int rank = i >> 13, rem = i & 8191;
    int kc = rem >> 9, ii = (rem >> 5) & 15, kk = rem & 31;
    whc[i] = f2bf(wh[(rank*16 + ii)*512 + kc*32 + kk]);
  }
  for (int i = tid; i < 512*1024; i += nth) {
    int rank = i >> 14, rem = i & 16383;
    int kc = rem >> 9, ii = (rem >> 5) & 15, kk = rem & 31;
    wpv[i] = f2bf(pvw[(rank*16 + ii)*1024 + kc*32 + kk]);
  }
  for (int i = tid; i < 512*1024; i += nth) s1b[i] = f2bf(sw1[i]);
  for (int i = tid; i < 256*512; i += nth) s2b[i] = f2bf(sw2[i]);
  if (tid < 256) ((uint32_t*)(ws + OFF_BAR))[tid] = 0u;
}

// ---------------------------------------------------------------------------
// K_rn: rn[b][e] = 1 / max(||emb[ids[b,:]][e]||_2 over s, 1e-12)
// ---------------------------------------------------------------------------
__global__ __launch_bounds__(256, 1) void k_rn(const int* __restrict__ ids,
                                               const float* __restrict__ emb,
                                               uint8_t* __restrict__ ws) {
  float* rn = (float*)(ws + OFF_RN);
  int b = blockIdx.x;
  int e = threadIdx.x;
  const int* idr = ids + (size_t)b * S_;
  float acc = 0.f;
  for (int s = 0; s < S_; ++s) {
    int id = idr[s];
    float v = emb[(size_t)id * EMB_ + e];
    acc += v * v;
  }
  rn[b * EMB_ + e] = 1.f / fmaxf(sqrtf(acc), 1e-12f);
}

// ---------------------------------------------------------------------------
// K_rix: ri_x[s][r][b] (bf16, stored in d_out) = (emb[ids[b,s]]*rn[b]) @ w_i_x^T
// ---------------------------------------------------------------------------
__global__ __launch_bounds__(256, 1) void k_rix(const int* __restrict__ ids,
                                                const float* __restrict__ emb,
                                                const uint8_t* __restrict__ ws,
                                                uint16_t* __restrict__ rix) {
  const uint16_t* wix = (const uint16_t*)(ws + OFF_WIX);
  const float* rn = (const float*)(ws + OFF_RN);
  int blk = blockIdx.x;
  int s = blk >> 3;
  int b16 = (blk & 7) * 16;
  int lane = threadIdx.x & 63;
  int wv = threadIdx.x >> 6;
  int bl = lane & 15, kg = lane >> 4;
  int b = b16 + bl;
  int id = ids[(size_t)b * S_ + s];
  const float* erow = emb + (size_t)id * EMB_;
  const float* rrow = rn + (size_t)b * EMB_;
  bf16x8 af[8];
#pragma unroll
  for (int kc = 0; kc < 8; ++kc) {
    int k0 = kc * 32 + kg * 8;
#pragma unroll
    for (int j = 0; j < 8; ++j)
      af[kc][j] = (short)f2bf(erow[k0 + j] * rrow[k0 + j]);
  }
  f32x4 zero = {0.f, 0.f, 0.f, 0.f};
#pragma unroll
  for (int t = 0; t < 8; ++t) {
    int rt = wv * 8 + t;
    f32x4 acc = zero;
#pragma unroll
    for (int kc = 0; kc < 8; ++kc) {
      bf16x8 wf = *(const bf16x8*)(wix + (size_t)(rt * 16 + bl) * 256 + kc * 32 + kg * 8);
      acc = mfma16(wf, af[kc], acc);  // D[r][b]
    }
#pragma unroll
    for (int q = 0; q < 4; ++q) {
      int r = rt * 16 + kg * 4 + q;
      rix[(size_t)(s * 512 + r) * 128 + b16 + bl] = f2bf(acc[q]);
    }
  }
}

// ---------------------------------------------------------------------------
// fence-free group barrier: vmcnt drain + relaxed monotonic counter
// ---------------------------------------------------------------------------
__device__ __forceinline__ void bar_arrive(uint32_t* bar) {
  asm volatile("s_waitcnt vmcnt(0)" ::: "memory");  // payload stores reached MALL
  if (threadIdx.x == 0)
    __hip_atomic_fetch_add(bar, 1u, __ATOMIC_RELAXED, __HIP_MEMORY_SCOPE_AGENT);
}
__device__ __forceinline__ void bar_wait(uint32_t* bar, uint32_t target) {
  while (__hip_atomic_load(bar, __ATOMIC_RELAXED, __HIP_MEMORY_SCOPE_AGENT) < target)
    __builtin_amdgcn_s_sleep(1);
  asm volatile("" ::: "memory");  // compiler-only fence; payload ld are sc-bypass
}

// ---------------------------------------------------------------------------
// K_scan: sequential pass. 256 WGs x 64 thr = 8 groups (XCD-ish) x 32 CUs.
// Weights LDS-resident; all cross-CU payload via MALL-direct atomics.
// ---------------------------------------------------------------------------
__global__ __launch_bounds__(64, 1) void k_scan(const float* __restrict__ opsw,
                                                const float* __restrict__ pvb,
                                                uint8_t* __restrict__ ws,
                                                const uint16_t* __restrict__ rix) {
  extern __shared__ uint8_t lds[];
  const int lane = threadIdx.x;
  const int bl = lane & 15;
  const int kg = lane >> 4;
  const int g = blockIdx.x & 7;
  const int rank = blockIdx.x >> 3;
  const int b0 = g * 16;

  {  // stage weight slices into LDS (layouts match: straight copy)
    const u32x4* swip = (const u32x4*)(ws + OFF_WIP) + (size_t)rank * 1024;
    const u32x4* swh  = (const u32x4*)(ws + OFF_WH)  + (size_t)rank * 1024;
    const u32x4* swpv = (const u32x4*)(ws + OFF_WPV) + (size_t)rank * 2048;
    u32x4* dwip = (u32x4*)lds;
    u32x4* dwh  = (u32x4*)(lds + 16384);
    u32x4* dwpv = (u32x4*)(lds + 32768);
    for (int i = lane; i < 1024; i += 64) dwip[i] = swip[i];
    for (int i = lane; i < 1024; i += 64) dwh[i] = swh[i];
    for (int i = lane; i < 2048; i += 64) dwpv[i] = swpv[i];
  }
  __syncthreads();

  float c1[4][6], c2[4][6], pb[4];
#pragma unroll
  for (int q = 0; q < 4; ++q) {
    int r = rank * 16 + kg * 4 + q;
#pragma unroll
    for (int t6 = 0; t6 < 6; ++t6) {
      c1[q][t6] = opsw[t6 * 1024 + r];
      c2[q][t6] = opsw[t6 * 1024 + 512 + r];
    }
    pb[q] = pvb[r];
  }
  const int ksown = rank >> 4;
  float stk[4][12];
#pragma unroll
  for (int q = 0; q < 4; ++q)
#pragma unroll
    for (int d = 0; d < 12; ++d) stk[q][d] = 0.f;

  uint8_t* hhbase = ws + OFF_HH;
  uint8_t* peeks = ws + OFF_PEEKS + (size_t)g * 16384;
  float* opp = (float*)(ws + OFF_OPP + (size_t)g * 12288);
  uint32_t* bar = (uint32_t*)(ws + OFF_BAR) + g * 32;

  const int kcA = rank >> 1;
  const int kA = (rank & 1) * 16;
  const uint8_t* ldwip = lds;
  const uint8_t* ldwh = lds + 16384;
  const uint8_t* ldwpv = lds + 32768;
  f32x4 zero = {0.f, 0.f, 0.f, 0.f};
  f32x4 rh_next = zero;  // rh(0) = 0 (h(-1)=0)

  for (int s = 0; s < S_; ++s) {
    uint8_t* hhs = hhbase + (size_t)s * 262144;
    // ---------------- Phase A: ri(peeks) + rh -> h1,h2 -> hh; ops partials --
    f32x4 ri = zero;
    if (s > 0) {
#pragma unroll
      for (int kc = 0; kc < 16; ++kc) {
        bf16x8 pk = ld_frag(peeks + kc * 1024 + bl * 64 + kg * 16);
        bf16x8 w1 = *(const bf16x8*)(ldwip + kc * 1024 + bl * 64 + kg * 16);
        ri = mfma16(w1, pk, ri);  // D[r][b]
      }
    }
    f32x4 rh = rh_next;
    float opq[6] = {0, 0, 0, 0, 0, 0};
    uint32_t h1lo = 0, h1hi = 0, h2lo = 0, h2hi = 0;
#pragma unroll
    for (int q = 0; q < 4; ++q) {
      int r = rank * 16 + kg * 4 + q;
      float rx = bf2f(rix[(size_t)(s * 512 + r) * 128 + b0 + bl]);
      float a = ri[q] + rx + rh[q];
      float b2 = ri[q] + rx - rh[q];
      float h1 = a > 0.f ? a : 0.f;
      float h2 = b2 > 0.f ? b2 : 0.f;
#pragma unroll
      for (int t6 = 0; t6 < 6; ++t6) opq[t6] += h1 * c1[q][t6] + h2 * c2[q][t6];
      uint32_t u1 = f2bf(h1), u2 = f2bf(h2);
      if (q < 2) { h1lo |= u1 << (q * 16); h2lo |= u2 << (q * 16); }
      else       { h1hi |= u1 << ((q - 2) * 16); h2hi |= u2 << ((q - 2) * 16); }
    }
    st_u64(hhs + (size_t)kcA * 8192 + (b0 + bl) * 64 + kA * 2 + kg * 8,
           (uint64_t)h1lo | ((uint64_t)h1hi << 32));
    st_u64(hhs + (size_t)(16 + kcA) * 8192 + (b0 + bl) * 64 + kA * 2 + kg * 8,
           (uint64_t)h2lo | ((uint64_t)h2hi << 32));
#pragma unroll
    for (int t6 = 0; t6 < 6; ++t6) {
      float v = opq[t6];
      v += __shfl_xor(v, 16, 64);
      v += __shfl_xor(v, 32, 64);
      opq[t6] = v;
    }
    if (kg == 0) {
#pragma unroll
      for (int t6 = 0; t6 < 6; ++t6) st_f32a(opp + (rank * 6 + t6) * 16 + bl, opq[t6]);
    }
    bar_arrive(bar);
    bar_wait(bar, 32u * (uint32_t)(2 * s + 1));

    // ---------------- Phase B: ops softmax, pv, stack update, peeks --------
    float lg0 = 0.f, lg1 = 0.f, lg2 = 0.f;
#pragma unroll
    for (int i = 0; i < 8; ++i) {
      int cu = kg + i * 4;
      lg0 += ld_f32a(opp + (cu * 6 + ksown * 3 + 0) * 16 + bl);
      lg1 += ld_f32a(opp + (cu * 6 + ksown * 3 + 1) * 16 + bl);
      lg2 += ld_f32a(opp + (cu * 6 + ksown * 3 + 2) * 16 + bl);
    }
    lg0 += __shfl_xor(lg0, 16, 64); lg0 += __shfl_xor(lg0, 32, 64);
    lg1 += __shfl_xor(lg1, 16, 64); lg1 += __shfl_xor(lg1, 32, 64);
    lg2 += __shfl_xor(lg2, 16, 64); lg2 += __shfl_xor(lg2, 32, 64);
    float mx = fmaxf(lg0, fmaxf(lg1, lg2));
    float e0 = __expf(lg0 - mx), e1 = __expf(lg1 - mx), e2 = __expf(lg2 - mx);
    float rden = 1.f / (e0 + e1 + e2);
    float push = e0 * rden, pop = e1 * rden, nop = e2 * rden;

    f32x4 pv0 = zero, pv1 = zero;
#pragma unroll
    for (int kc = 0; kc < 32; kc += 2) {
      bf16x8 a0 = ld_frag(hhs + (size_t)kc * 8192 + (b0 + bl) * 64 + kg * 16);
      bf16x8 w0 = *(const bf16x8*)(ldwpv + kc * 1024 + bl * 64 + kg * 16);
      pv0 = mfma16(w0, a0, pv0);
      bf16x8 a1 = ld_frag(hhs + (size_t)(kc + 1) * 8192 + (b0 + bl) * 64 + kg * 16);
      bf16x8 w1 = *(const bf16x8*)(ldwpv + (kc + 1) * 1024 + bl * 64 + kg * 16);
      pv1 = mfma16(w1, a1, pv1);
    }
    uint32_t pklo = 0, pkhi = 0;
#pragma unroll
    for (int q = 0; q < 4; ++q) {
      float pvv = pv0[q] + pv1[q] + pb[q];
      float prev = stk[q][0];
      stk[q][0] = push * pvv + pop * stk[q][1] + nop * stk[q][0];
#pragma unroll
      for (int d = 1; d < 11; ++d) {
        float cur = stk[q][d];
        stk[q][d] = push * prev + pop * stk[q][d + 1] + nop * cur;
        prev = cur;
      }
      float last = stk[q][11];
      stk[q][11] = push * prev + nop * last;
      uint32_t up = f2bf(stk[q][0]);
      if (q < 2) pklo |= up << (q * 16); else pkhi |= up << ((q - 2) * 16);
    }
    st_u64(peeks + kcA * 1024 + bl * 64 + kA * 2 + kg * 8,
           (uint64_t)pklo | ((uint64_t)pkhi << 32));
    bar_arrive(bar);
    // --- hidden under barrier wait: prefetch next step's rh from hh(s) -----
    if (s + 1 < S_) {
      rh_next = zero;
#pragma unroll
      for (int kc = 0; kc < 16; ++kc) {
        bf16x8 hf = ld_frag(hhs + (size_t)kc * 8192 + (b0 + bl) * 64 + kg * 16);
        bf16x8 w2 = *(const bf16x8*)(ldwh + kc * 1024 + bl * 64 + kg * 16);
        rh_next = mfma16(w2, hf, rh_next);
      }
    }
    bar_wait(bar, 32u * (uint32_t)(2 * s + 2));
  }
}

// ---------------------------------------------------------------------------
// K_sem: deferred sem head. out = normalize(relu(hh@W1^T)@W2^T) over E.
// ---------------------------------------------------------------------------
__global__ __launch_bounds__(256, 1) void k_sem(const uint8_t* __restrict__ ws,
                                                float* __restrict__ out) {
  __shared__ uint16_t t1[2][16][16][32];
  __shared__ float nrm[2][16][2];
  int mt = blockIdx.x;
  int s = mt >> 2;
  int b0 = (mt & 3) * 32;
  int lane = threadIdx.x & 63, wv = threadIdx.x >> 6;
  int msub = wv >> 1, half = wv & 1;
  int bl = lane & 15, kg = lane >> 4;
  const uint8_t* hh = ws + OFF_HH + (size_t)s * 262144;
  const uint16_t* sw1 = (const uint16_t*)(ws + OFF_SW1);
  const uint16_t* sw2 = (const uint16_t*)(ws + OFF_SW2);
  f32x4 zero = {0.f, 0.f, 0.f, 0.f};

  f32x4 acc1[16];
#pragma unroll
  for (int nt = 0; nt < 16; ++nt) acc1[nt] = zero;
  for (int kc = 0; kc < 32; ++kc) {
    bf16x8 af = *(const bf16x8*)(hh + (size_t)kc * 8192 + (b0 + msub * 16 + bl) * 64 + kg * 16);
#pragma unroll
    for (int nt = 0; nt < 16; ++nt) {
      bf16x8 wf = *(const bf16x8*)(sw1 + (size_t)(half * 256 + nt * 16 + bl) * 1024 + kc * 32 + kg * 8);
      acc1[nt] = mfma16(wf, af, acc1[nt]);  // D[n][m]
    }
  }
#pragma unroll
  for (int nt = 0; nt < 16; ++nt) {
#pragma unroll
    for (int q = 0; q < 4; ++q) {
      int n = half * 256 + nt * 16 + kg * 4 + q;
      float v = acc1[nt][q];
      v = v > 0.f ? v : 0.f;
      t1[msub][n >> 5][bl][n & 31] = f2bf(v);
    }
  }
  __syncthreads();

  f32x4 acc2[8];
#pragma unroll
  for (int et = 0; et < 8; ++et) acc2[et] = zero;
#pragma unroll
  for (int kc = 0; kc < 16; ++kc) {
    bf16x8 tf = *(const bf16x8*)(&t1[msub][kc][bl][kg * 8]);
#pragma unroll
    for (int et = 0; et < 8; ++et) {
      bf16x8 wf = *(const bf16x8*)(sw2 + (size_t)(half * 128 + et * 16 + bl) * 512 + kc * 32 + kg * 8);
      acc2[et] = mfma16(tf, wf, acc2[et]);  // D[m][e]
    }
  }
  float ss[4] = {0, 0, 0, 0};
#pragma unroll
  for (int et = 0; et < 8; ++et)
#pragma unroll
    for (int q = 0; q < 4; ++q) ss[q] += acc2[et][q] * acc2[et][q];
#pragma unroll
  for (int q = 0; q < 4; ++q) {
    float v = ss[q];
    v += __shfl_xor(v, 1, 16);
    v += __shfl_xor(v, 2, 16);
    v += __shfl_xor(v, 4, 16);
    v += __shfl_xor(v, 8, 16);
    ss[q] = v;
  }
  if (bl == 0) {
#pragma unroll
    for (int q = 0; q < 4; ++q) nrm[msub][kg * 4 + q][half] = ss[q];
  }
  __syncthreads();
  float sc[4];
#pragma unroll
  for (int q = 0; q < 4; ++q) {
    float tot = nrm[msub][kg * 4 + q][0] + nrm[msub][kg * 4 + q][1];
    sc[q] = 1.f / fmaxf(sqrtf(tot), 1e-12f);
  }
#pragma unroll
  for (int et = 0; et < 8; ++et) {
    int e = half * 128 + et * 16 + bl;
#pragma unroll
    for (int q = 0; q < 4; ++q) {
      int b = b0 + msub * 16 + kg * 4 + q;
      out[((size_t)b * S_ + s) * EMB_ + e] = acc2[et][q] * sc[q];
    }
  }
}

// ---------------------------------------------------------------------------
extern "C" void kernel_launch(void* const* d_in, const int* in_sizes, int n_in,
                              void* d_out, int out_size, void* d_ws, size_t ws_size,
                              hipStream_t stream) {
  (void)in_sizes; (void)n_in; (void)out_size; (void)ws_size;
  const int* ids = (const int*)d_in[0];
  const float* emb = (const float*)d_in[1];
  const float* wi = (const float*)d_in[2];
  const float* wh = (const float*)d_in[3];
  const float* sw1 = (const float*)d_in[4];
  const float* sw2 = (const float*)d_in[5];
  const float* pvw = (const float*)d_in[6];
  const float* pvb = (const float*)d_in[7];
  const float* opsw = (const float*)d_in[8];
  uint8_t* ws = (uint8_t*)d_ws;
  float* out = (float*)d_out;
  uint16_t* rix = (uint16_t*)d_out;  // ri_x (128MB bf16) lives in d_out until k_sem

  hipLaunchKernelGGL(k_conv, dim3(256), dim3(256), 0, stream, wi, wh, pvw, sw1, sw2, ws);
  hipLaunchKernelGGL(k_rn, dim3(128), dim3(256), 0, stream, ids, emb, ws);
  hipLaunchKernelGGL(k_rix, dim3(8192), dim3(256), 0, stream, ids, emb, ws, rix);
  hipLaunchKernelGGL(k_scan, dim3(256), dim3(64), 65536, stream, opsw, pvb, ws, rix);
  hipLaunchKernelGGL(k_sem, dim3(4096), dim3(256), 0, stream, ws, out);
}